// Round 1
// baseline (184.432 us; speedup 1.0000x reference)
//
#include <hip/hip_runtime.h>
#include <stdint.h>
#include <math.h>

// RpnLoss: BATCH=4096 samples, A = 5*17*17 = 1445 anchors.
// R4: TWO WAVES PER SAMPLE (wave pair splits the 23 anchor-iterations 12/11).
// Grid 2048 blocks x 256 thr = 8192 waves -> 8 waves/SIMD (was 4): latency
// hiding doubles and the per-wave serial chain halves. Wave 0 of a pair does
// the histogram scan + boundary bin while wave 1 concurrently does positive
// ranking + reg loss. Per-wave PRIVATE 256-bin histograms (no cross-wave
// atomic contention, no zeroing barrier); merged during the scan.
// cv[] cache dropped (VGPR <= 64 for 8 waves/SIMD); the ~k_n selected cls
// values are re-read from L2 in the classify phase.
// PRNG (bit-exact, verified R1/R2): key_i = threefry((0,42),(0,i));
// kpos[n]=key_n, kneg[n]=key_{N+n}; draw j: r = (o0^o1 of threefry(key,(0,j)))>>9.

#define A_TOT 1445
#define SPB 2           // samples per block (2 waves each -> 4 waves/block)
#define NH 12           // unrolled iterations per half-wave (h=0: t 0..11, h=1: t 12..23, tail auto-invalid)
#define POSW_MAX 32     // per-wave positive list cap (geometric bound on n_pos total is ~26)
#define CAND_MAX 128

__device__ __forceinline__ void tf2x32(uint32_t k0, uint32_t k1, uint32_t x0, uint32_t x1,
                                       uint32_t& o0, uint32_t& o1)
{
  const uint32_t k2 = k0 ^ k1 ^ 0x1BD11BDAu;
  x0 += k0; x1 += k1;
#define TFR(r) { x0 += x1; x1 = __builtin_rotateleft32(x1, (r)); x1 ^= x0; }
  TFR(13) TFR(15) TFR(26) TFR(6)
  x0 += k1; x1 += k2 + 1u;
  TFR(17) TFR(29) TFR(16) TFR(24)
  x0 += k2; x1 += k0 + 2u;
  TFR(13) TFR(15) TFR(26) TFR(6)
  x0 += k0; x1 += k1 + 3u;
  TFR(17) TFR(29) TFR(16) TFR(24)
  x0 += k1; x1 += k2 + 4u;
  TFR(13) TFR(15) TFR(26) TFR(6)
  x0 += k2; x1 += k0 + 5u;
#undef TFR
  o0 = x0; o1 = x1;
}

// logaddexp(0,x) via HW exp/log; rel err ~2^-21 << threshold (passed R2).
__device__ __forceinline__ float lae0(float x){
  return fmaxf(x, 0.0f) + __logf(1.0f + __expf(-fabsf(x)));
}

__global__ void __launch_bounds__(256, 8) rpn_loss_kernel(
    const float* __restrict__ pred_cls, const float* __restrict__ pred_reg,
    const float* __restrict__ gt_bbox, const float* __restrict__ anchor_center,
    const float* __restrict__ anchor_corner,
    float* __restrict__ part,   // [3][N] partials: lc, lr, acc
    int N)
{
  __shared__ uint32_t s_hist[SPB][2][256];   // per-wave private histograms
  __shared__ uint32_t s_cand[SPB][CAND_MAX];
  __shared__ uint32_t s_pidx[SPB][2][POSW_MAX];
  __shared__ float    s_pcls[SPB][2][POSW_MAX];
  __shared__ uint32_t s_pcnt[SPB][2];
  __shared__ uint32_t s_ccnt[SPB];
  __shared__ int      s_share[SPB][3];       // k_n, Bb, m
  __shared__ float    s_red[SPB][2][3];

  const int w    = threadIdx.x >> 6;   // 0..3
  const int lane = threadIdx.x & 63;
  const int s    = w >> 1;             // sample slot in block
  const int h    = w & 1;              // half index within the pair
  const int n    = blockIdx.x * SPB + s;

  // zero OWN private histogram + pos counter (same-wave LDS ops are ordered;
  // cross-wave reads only happen after barrier B1)
  #pragma unroll
  for (int b = 0; b < 4; b++) s_hist[s][h][lane * 4 + b] = 0u;
  if (lane == 0) s_pcnt[s][h] = 0u;

  const float g0 = gt_bbox[4 * n + 0];
  const float g1 = gt_bbox[4 * n + 1];
  const float g2 = gt_bbox[4 * n + 2];
  const float g3 = gt_bbox[4 * n + 3];
  const float area_a = (g2 - g0) * (g3 - g1);

  uint32_t kn0, kn1;
  tf2x32(0u, 42u, 0u, (uint32_t)(N + n), kn0, kn1);

  const float*  cls_base = pred_cls + (size_t)n * A_TOT;
  const float4* cornv = (const float4*)anchor_corner;

  uint32_t rn[NH];            // 0xFFFFFFFF sentinel for non-negative anchors
  float accc = 0.0f;
  const int tbase = h * NH;   // h=0: t 0..11; h=1: t 12..23 (t=23 fully invalid)

  // ---- Phase A (own half): IoU + neg-key hash + private histogram +
  //      positive compaction + accuracy
  #pragma unroll
  for (int tt = 0; tt < NH; tt++){
    const int j = lane + 64 * (tbase + tt);
    const bool valid = (j < A_TOT);
    const int jc = valid ? j : (A_TOT - 1);
    float4 cr = cornv[jc];
    float c = cls_base[jc];
    float ltx = fmaxf(g0, cr.x), lty = fmaxf(g1, cr.y);
    float rbx = fminf(g2, cr.z), rby = fminf(g3, cr.w);
    float inter = fmaxf(rbx - ltx, 0.0f) * fmaxf(rby - lty, 0.0f);
    float area_b = (cr.z - cr.x) * (cr.w - cr.y);
    float iou = inter / (area_a + area_b - inter);
    bool pos = valid && (iou > 0.6f);
    bool neg = valid && (iou < 0.3f);
    uint32_t o0, o1;
    tf2x32(kn0, kn1, 0u, (uint32_t)j, o0, o1);
    uint32_t r = (o0 ^ o1) >> 9;       // 23-bit rank value
    rn[tt] = neg ? r : 0xFFFFFFFFu;    // sentinel: bin = r>>15 >= 256 never selected
    if (neg) atomicAdd(&s_hist[s][h][r >> 15], 1u);
    if (pos){
      uint32_t id = atomicAdd(&s_pcnt[s][h], 1u);
      if (id < POSW_MAX){ s_pidx[s][h][id] = (uint32_t)j; s_pcls[s][h][id] = c; }
    }
    if (valid) accc += ((c >= 0.6f) == pos) ? 1.0f : 0.0f;
  }
  __syncthreads();   // B1: histograms + positive lists complete

  const int n_pos = min((int)s_pcnt[s][0], POSW_MAX) + min((int)s_pcnt[s][1], POSW_MAX);
  float lc = 0.0f, lr = 0.0f;

  if (h == 0){
    // ---- wave 0: zero cand counter; merge+scan histogram; boundary bin
    if (lane == 0) s_ccnt[s] = 0u;
    const int b = lane * 4;
    uint32_t v0 = s_hist[s][0][b]     + s_hist[s][1][b];
    uint32_t v1 = s_hist[s][0][b + 1] + s_hist[s][1][b + 1];
    uint32_t v2 = s_hist[s][0][b + 2] + s_hist[s][1][b + 2];
    uint32_t v3 = s_hist[s][0][b + 3] + s_hist[s][1][b + 3];
    uint32_t S0 = v0, S1 = S0 + v1, S2 = S1 + v2, S3 = S2 + v3;
    uint32_t x = S3;
    #pragma unroll
    for (int off = 1; off < 64; off <<= 1){
      uint32_t tmp = __shfl_up(x, off, 64);
      if (lane >= off) x += tmp;
    }
    uint32_t excl = x - S3;
    S0 += excl; S1 += excl; S2 += excl; S3 += excl;
    s_hist[s][0][b] = S0; s_hist[s][0][b+1] = S1; s_hist[s][0][b+2] = S2; s_hist[s][0][b+3] = S3;
    const int n_neg = (int)__shfl(S3, 63, 64);
    const int k_n_w = min(n_neg, (n_pos > 0) ? 3 * n_pos : 48);
    int Bb_w = 256, m_w = 0;
    if (k_n_w > 0){
      unsigned long long bal = __ballot(S3 >= (uint32_t)k_n_w);
      int fl = __ffsll(bal) - 1;       // exists: lane63 S3=n_neg>=k_n
      uint32_t t0 = __shfl(S0, fl, 64), t1 = __shfl(S1, fl, 64), t2 = __shfl(S2, fl, 64);
      int sub = (t0 >= (uint32_t)k_n_w) ? 0 : ((t1 >= (uint32_t)k_n_w) ? 1 : ((t2 >= (uint32_t)k_n_w) ? 2 : 3));
      Bb_w = fl * 4 + sub;
      uint32_t before = (Bb_w == 0) ? 0u : s_hist[s][0][Bb_w - 1];  // same-wave ordered
      m_w = k_n_w - (int)before;
    }
    if (lane == 0){ s_share[s][0] = k_n_w; s_share[s][1] = Bb_w; s_share[s][2] = m_w; }
  } else {
    // ---- wave 1 (concurrent): positives ranking, bce + reg loss
    if (n_pos > 0){
      uint32_t kp0, kp1;
      tf2x32(0u, 42u, 0u, (uint32_t)n, kp0, kp1);
      const int c0 = min((int)s_pcnt[s][0], POSW_MAX);
      uint32_t myr = 0u, myj = 0u; float myc = 0.0f;
      if (lane < n_pos){
        const int src = (lane < c0) ? 0 : 1;
        const int idx = (lane < c0) ? lane : (lane - c0);
        myj = s_pidx[s][src][idx];
        myc = s_pcls[s][src][idx];
        uint32_t o0, o1;
        tf2x32(kp0, kp1, 0u, myj, o0, o1);
        myr = (o0 ^ o1) >> 9;
      }
      int rank = 0;
      for (int l = 0; l < n_pos; l++){
        uint32_t r2 = __shfl(myr, l, 64), j2 = __shfl(myj, l, 64);
        if (lane < n_pos && (r2 < myr || (r2 == myr && j2 < myj))) rank++;
      }
      const int k_p = min(n_pos, 16);
      if (lane < n_pos){
        if (rank < k_p) lc += lae0(-myc);
        float gcx = (g0 + g2) * 0.5f, gcy = (g1 + g3) * 0.5f;
        float gw = g2 - g0, gh = g3 - g1;
        float4 ce = ((const float4*)anchor_center)[myj];
        const float* reg_base = pred_reg + (size_t)n * 4 * A_TOT;
        float t0 = (gcx - ce.x) / ce.z;
        float t1 = (gcy - ce.y) / ce.w;
        float t2 = __logf(gw / ce.z);
        float t3 = __logf(gh / ce.w);
        float d0 = reg_base[myj]             - t0;
        float d1 = reg_base[A_TOT + myj]     - t1;
        float d2 = reg_base[2 * A_TOT + myj] - t2;
        float d3 = reg_base[3 * A_TOT + myj] - t3;
        lr = d0 * d0 + d1 * d1 + d2 * d2 + d3 * d3;
      }
    }
  }
  __syncthreads();   // B2: k_n/Bb/m visible; cand counter zeroed

  const int k_n = s_share[s][0];
  const int Bb  = s_share[s][1];
  // ---- classify own half from registers; cls re-read (L2-hot) only where selected
  if (k_n > 0){
    #pragma unroll
    for (int tt = 0; tt < NH; tt++){
      const uint32_t r = rn[tt];
      const int bin = (int)(r >> 15);
      if (bin < Bb){
        lc += lae0(cls_base[lane + 64 * (tbase + tt)]);
      } else if (bin == Bb){
        uint32_t id = atomicAdd(&s_ccnt[s], 1u);
        if (id < CAND_MAX)
          s_cand[s][id] = ((r & 0x7FFFu) << 11) | (uint32_t)(lane + 64 * (tbase + tt));
      }
    }
  }
  __syncthreads();   // B3: candidates visible to both waves

  if (k_n > 0){
    const int m = s_share[s][2];
    const int L = min((int)s_ccnt[s], CAND_MAX);
    for (int c = h * 64 + lane; c < L; c += 128){   // split across the wave pair
      uint32_t my = s_cand[s][c];
      int rank = 0;
      for (int l = 0; l < L; l++) rank += (s_cand[s][l] < my) ? 1 : 0;  // broadcast reads
      if (rank < m) lc += lae0(cls_base[my & 0x7FFu]);
    }
  }

  // ---- per-wave reduce, then cross-wave combine via LDS
  float v0 = lc, v1 = lr, v2 = accc;
  #pragma unroll
  for (int off = 32; off > 0; off >>= 1){
    v0 += __shfl_down(v0, off, 64);
    v1 += __shfl_down(v1, off, 64);
    v2 += __shfl_down(v2, off, 64);
  }
  if (lane == 0){ s_red[s][h][0] = v0; s_red[s][h][1] = v1; s_red[s][h][2] = v2; }
  __syncthreads();   // B4

  if (h == 0 && lane == 0){
    float LC = s_red[s][0][0] + s_red[s][1][0];
    float LR = s_red[s][0][1] + s_red[s][1][1];
    float AC = s_red[s][0][2] + s_red[s][1][2];
    const int k_p = min(n_pos, 16);
    int denom = k_p + k_n; if (denom < 1) denom = 1;
    part[n]         = LC / (float)denom;
    part[N + n]     = (n_pos > 0) ? (LR / (4.0f * (float)n_pos)) : 0.0f;
    part[2 * N + n] = AC * (1.0f / (float)A_TOT);
  }
}

__global__ void __launch_bounds__(256) reduce_kernel(const float* __restrict__ part,
                                                     float* __restrict__ out, int N)
{
  const int tid = threadIdx.x;
  float lc = 0.0f, lr = 0.0f, ac = 0.0f;
  for (int i = tid; i < N; i += 256){
    lc += part[i];
    lr += part[N + i];
    ac += part[2 * N + i];
  }
  __shared__ float s[12];
  #pragma unroll
  for (int off = 32; off > 0; off >>= 1){
    lc += __shfl_down(lc, off, 64);
    lr += __shfl_down(lr, off, 64);
    ac += __shfl_down(ac, off, 64);
  }
  const int wave = tid >> 6, lane = tid & 63;
  if (lane == 0){ s[wave] = lc; s[4 + wave] = lr; s[8 + wave] = ac; }
  __syncthreads();
  if (tid == 0){
    float LC = s[0] + s[1] + s[2] + s[3];
    float LR = s[4] + s[5] + s[6] + s[7];
    float AC = s[8] + s[9] + s[10] + s[11];
    float inv = 1.0f / (float)N;
    LC *= inv; LR *= inv; AC *= inv;
    out[0] = LC + LR;
    out[1] = LC;
    out[2] = LR;
    out[3] = AC;
  }
}

extern "C" void kernel_launch(void* const* d_in, const int* in_sizes, int n_in,
                              void* d_out, int out_size, void* d_ws, size_t ws_size,
                              hipStream_t stream)
{
  const float* pred_cls = (const float*)d_in[0];
  const float* pred_reg = (const float*)d_in[1];
  const float* gt_bbox  = (const float*)d_in[2];
  const float* a_center = (const float*)d_in[3];
  const float* a_corner = (const float*)d_in[4];
  float* part = (float*)d_ws;            // 3*N floats
  float* out  = (float*)d_out;

  const int N = in_sizes[2] / 4;         // 4096

  hipLaunchKernelGGL(rpn_loss_kernel, dim3(N / SPB), dim3(SPB * 2 * 64), 0, stream,
                     pred_cls, pred_reg, gt_bbox, a_center, a_corner, part, N);
  hipLaunchKernelGGL(reduce_kernel, dim3(1), dim3(256), 0, stream, part, out, N);
}

// Round 2
// 178.954 us; speedup vs baseline: 1.0306x; 1.0306x over previous
//
#include <hip/hip_runtime.h>
#include <stdint.h>
#include <math.h>

// RpnLoss: BATCH=4096 samples, A = 5*17*17 = 1445 anchors.
// R5: same two-waves-per-sample structure as R4 (grid 8192 waves -> 8/SIMD
// grid cap; per-wave serial chain halved; wave0 scan || wave1 pos-ranking).
// FIX vs R4: __launch_bounds__(256, 8) forced a ~32-VGPR budget and the
// allocator spilled rn[] + live state to SCRATCH (WRITE_SIZE 96KB -> 49MB,
// occupancy 1.7%, 157us). Relax to (256, 6): cap ~85 VGPRs, natural need is
// ~55-60, so no memory spill; if total (VGPR+AGPR) lands <=64 the HW still
// grants 8 waves/SIMD.
// PRNG (bit-exact, verified R1/R2): key_i = threefry((0,42),(0,i));
// kpos[n]=key_n, kneg[n]=key_{N+n}; draw j: r = (o0^o1 of threefry(key,(0,j)))>>9.

#define A_TOT 1445
#define SPB 2           // samples per block (2 waves each -> 4 waves/block)
#define NH 12           // unrolled iterations per half-wave (h=0: t 0..11, h=1: t 12..23)
#define POSW_MAX 32     // per-wave positive list cap (geometric bound on n_pos total is ~26)
#define CAND_MAX 128

__device__ __forceinline__ void tf2x32(uint32_t k0, uint32_t k1, uint32_t x0, uint32_t x1,
                                       uint32_t& o0, uint32_t& o1)
{
  const uint32_t k2 = k0 ^ k1 ^ 0x1BD11BDAu;
  x0 += k0; x1 += k1;
#define TFR(r) { x0 += x1; x1 = __builtin_rotateleft32(x1, (r)); x1 ^= x0; }
  TFR(13) TFR(15) TFR(26) TFR(6)
  x0 += k1; x1 += k2 + 1u;
  TFR(17) TFR(29) TFR(16) TFR(24)
  x0 += k2; x1 += k0 + 2u;
  TFR(13) TFR(15) TFR(26) TFR(6)
  x0 += k0; x1 += k1 + 3u;
  TFR(17) TFR(29) TFR(16) TFR(24)
  x0 += k1; x1 += k2 + 4u;
  TFR(13) TFR(15) TFR(26) TFR(6)
  x0 += k2; x1 += k0 + 5u;
#undef TFR
  o0 = x0; o1 = x1;
}

// logaddexp(0,x) via HW exp/log; rel err ~2^-21 << threshold (passed R2).
__device__ __forceinline__ float lae0(float x){
  return fmaxf(x, 0.0f) + __logf(1.0f + __expf(-fabsf(x)));
}

__global__ void __launch_bounds__(256, 6) rpn_loss_kernel(
    const float* __restrict__ pred_cls, const float* __restrict__ pred_reg,
    const float* __restrict__ gt_bbox, const float* __restrict__ anchor_center,
    const float* __restrict__ anchor_corner,
    float* __restrict__ part,   // [3][N] partials: lc, lr, acc
    int N)
{
  __shared__ uint32_t s_hist[SPB][2][256];   // per-wave private histograms
  __shared__ uint32_t s_cand[SPB][CAND_MAX];
  __shared__ uint32_t s_pidx[SPB][2][POSW_MAX];
  __shared__ float    s_pcls[SPB][2][POSW_MAX];
  __shared__ uint32_t s_pcnt[SPB][2];
  __shared__ uint32_t s_ccnt[SPB];
  __shared__ int      s_share[SPB][3];       // k_n, Bb, m
  __shared__ float    s_red[SPB][2][3];

  const int w    = threadIdx.x >> 6;   // 0..3
  const int lane = threadIdx.x & 63;
  const int s    = w >> 1;             // sample slot in block
  const int h    = w & 1;              // half index within the pair
  const int n    = blockIdx.x * SPB + s;

  // zero OWN private histogram + pos counter (same-wave LDS ops are ordered;
  // cross-wave reads only happen after barrier B1)
  #pragma unroll
  for (int b = 0; b < 4; b++) s_hist[s][h][lane * 4 + b] = 0u;
  if (lane == 0) s_pcnt[s][h] = 0u;

  const float g0 = gt_bbox[4 * n + 0];
  const float g1 = gt_bbox[4 * n + 1];
  const float g2 = gt_bbox[4 * n + 2];
  const float g3 = gt_bbox[4 * n + 3];
  const float area_a = (g2 - g0) * (g3 - g1);

  uint32_t kn0, kn1;
  tf2x32(0u, 42u, 0u, (uint32_t)(N + n), kn0, kn1);

  const float*  cls_base = pred_cls + (size_t)n * A_TOT;
  const float4* cornv = (const float4*)anchor_corner;

  uint32_t rn[NH];            // 0xFFFFFFFF sentinel for non-negative anchors
  float accc = 0.0f;
  const int tbase = h * NH;   // h=0: t 0..11; h=1: t 12..23 (t=23 fully invalid)

  // ---- Phase A (own half): IoU + neg-key hash + private histogram +
  //      positive compaction + accuracy
  #pragma unroll
  for (int tt = 0; tt < NH; tt++){
    const int j = lane + 64 * (tbase + tt);
    const bool valid = (j < A_TOT);
    const int jc = valid ? j : (A_TOT - 1);
    float4 cr = cornv[jc];
    float c = cls_base[jc];
    float ltx = fmaxf(g0, cr.x), lty = fmaxf(g1, cr.y);
    float rbx = fminf(g2, cr.z), rby = fminf(g3, cr.w);
    float inter = fmaxf(rbx - ltx, 0.0f) * fmaxf(rby - lty, 0.0f);
    float area_b = (cr.z - cr.x) * (cr.w - cr.y);
    float iou = inter / (area_a + area_b - inter);
    bool pos = valid && (iou > 0.6f);
    bool neg = valid && (iou < 0.3f);
    uint32_t o0, o1;
    tf2x32(kn0, kn1, 0u, (uint32_t)j, o0, o1);
    uint32_t r = (o0 ^ o1) >> 9;       // 23-bit rank value
    rn[tt] = neg ? r : 0xFFFFFFFFu;    // sentinel: bin = r>>15 >= 256 never selected
    if (neg) atomicAdd(&s_hist[s][h][r >> 15], 1u);
    if (pos){
      uint32_t id = atomicAdd(&s_pcnt[s][h], 1u);
      if (id < POSW_MAX){ s_pidx[s][h][id] = (uint32_t)j; s_pcls[s][h][id] = c; }
    }
    if (valid) accc += ((c >= 0.6f) == pos) ? 1.0f : 0.0f;
  }
  __syncthreads();   // B1: histograms + positive lists complete

  const int n_pos = min((int)s_pcnt[s][0], POSW_MAX) + min((int)s_pcnt[s][1], POSW_MAX);
  float lc = 0.0f, lr = 0.0f;

  if (h == 0){
    // ---- wave 0: zero cand counter; merge+scan histogram; boundary bin
    if (lane == 0) s_ccnt[s] = 0u;
    const int b = lane * 4;
    uint32_t v0 = s_hist[s][0][b]     + s_hist[s][1][b];
    uint32_t v1 = s_hist[s][0][b + 1] + s_hist[s][1][b + 1];
    uint32_t v2 = s_hist[s][0][b + 2] + s_hist[s][1][b + 2];
    uint32_t v3 = s_hist[s][0][b + 3] + s_hist[s][1][b + 3];
    uint32_t S0 = v0, S1 = S0 + v1, S2 = S1 + v2, S3 = S2 + v3;
    uint32_t x = S3;
    #pragma unroll
    for (int off = 1; off < 64; off <<= 1){
      uint32_t tmp = __shfl_up(x, off, 64);
      if (lane >= off) x += tmp;
    }
    uint32_t excl = x - S3;
    S0 += excl; S1 += excl; S2 += excl; S3 += excl;
    s_hist[s][0][b] = S0; s_hist[s][0][b+1] = S1; s_hist[s][0][b+2] = S2; s_hist[s][0][b+3] = S3;
    const int n_neg = (int)__shfl(S3, 63, 64);
    const int k_n_w = min(n_neg, (n_pos > 0) ? 3 * n_pos : 48);
    int Bb_w = 256, m_w = 0;
    if (k_n_w > 0){
      unsigned long long bal = __ballot(S3 >= (uint32_t)k_n_w);
      int fl = __ffsll(bal) - 1;       // exists: lane63 S3=n_neg>=k_n
      uint32_t t0 = __shfl(S0, fl, 64), t1 = __shfl(S1, fl, 64), t2 = __shfl(S2, fl, 64);
      int sub = (t0 >= (uint32_t)k_n_w) ? 0 : ((t1 >= (uint32_t)k_n_w) ? 1 : ((t2 >= (uint32_t)k_n_w) ? 2 : 3));
      Bb_w = fl * 4 + sub;
      uint32_t before = (Bb_w == 0) ? 0u : s_hist[s][0][Bb_w - 1];  // same-wave ordered
      m_w = k_n_w - (int)before;
    }
    if (lane == 0){ s_share[s][0] = k_n_w; s_share[s][1] = Bb_w; s_share[s][2] = m_w; }
  } else {
    // ---- wave 1 (concurrent): positives ranking, bce + reg loss
    if (n_pos > 0){
      uint32_t kp0, kp1;
      tf2x32(0u, 42u, 0u, (uint32_t)n, kp0, kp1);
      const int c0 = min((int)s_pcnt[s][0], POSW_MAX);
      uint32_t myr = 0u, myj = 0u; float myc = 0.0f;
      if (lane < n_pos){
        const int src = (lane < c0) ? 0 : 1;
        const int idx = (lane < c0) ? lane : (lane - c0);
        myj = s_pidx[s][src][idx];
        myc = s_pcls[s][src][idx];
        uint32_t o0, o1;
        tf2x32(kp0, kp1, 0u, myj, o0, o1);
        myr = (o0 ^ o1) >> 9;
      }
      int rank = 0;
      for (int l = 0; l < n_pos; l++){
        uint32_t r2 = __shfl(myr, l, 64), j2 = __shfl(myj, l, 64);
        if (lane < n_pos && (r2 < myr || (r2 == myr && j2 < myj))) rank++;
      }
      const int k_p = min(n_pos, 16);
      if (lane < n_pos){
        if (rank < k_p) lc += lae0(-myc);
        float gcx = (g0 + g2) * 0.5f, gcy = (g1 + g3) * 0.5f;
        float gw = g2 - g0, gh = g3 - g1;
        float4 ce = ((const float4*)anchor_center)[myj];
        const float* reg_base = pred_reg + (size_t)n * 4 * A_TOT;
        float t0 = (gcx - ce.x) / ce.z;
        float t1 = (gcy - ce.y) / ce.w;
        float t2 = __logf(gw / ce.z);
        float t3 = __logf(gh / ce.w);
        float d0 = reg_base[myj]             - t0;
        float d1 = reg_base[A_TOT + myj]     - t1;
        float d2 = reg_base[2 * A_TOT + myj] - t2;
        float d3 = reg_base[3 * A_TOT + myj] - t3;
        lr = d0 * d0 + d1 * d1 + d2 * d2 + d3 * d3;
      }
    }
  }
  __syncthreads();   // B2: k_n/Bb/m visible; cand counter zeroed

  const int k_n = s_share[s][0];
  const int Bb  = s_share[s][1];
  // ---- classify own half from registers; cls re-read (L2-hot) only where selected
  if (k_n > 0){
    #pragma unroll
    for (int tt = 0; tt < NH; tt++){
      const uint32_t r = rn[tt];
      const int bin = (int)(r >> 15);
      if (bin < Bb){
        lc += lae0(cls_base[lane + 64 * (tbase + tt)]);
      } else if (bin == Bb){
        uint32_t id = atomicAdd(&s_ccnt[s], 1u);
        if (id < CAND_MAX)
          s_cand[s][id] = ((r & 0x7FFFu) << 11) | (uint32_t)(lane + 64 * (tbase + tt));
      }
    }
  }
  __syncthreads();   // B3: candidates visible to both waves

  if (k_n > 0){
    const int m = s_share[s][2];
    const int L = min((int)s_ccnt[s], CAND_MAX);
    for (int c = h * 64 + lane; c < L; c += 128){   // split across the wave pair
      uint32_t my = s_cand[s][c];
      int rank = 0;
      for (int l = 0; l < L; l++) rank += (s_cand[s][l] < my) ? 1 : 0;  // broadcast reads
      if (rank < m) lc += lae0(cls_base[my & 0x7FFu]);
    }
  }

  // ---- per-wave reduce, then cross-wave combine via LDS
  float v0 = lc, v1 = lr, v2 = accc;
  #pragma unroll
  for (int off = 32; off > 0; off >>= 1){
    v0 += __shfl_down(v0, off, 64);
    v1 += __shfl_down(v1, off, 64);
    v2 += __shfl_down(v2, off, 64);
  }
  if (lane == 0){ s_red[s][h][0] = v0; s_red[s][h][1] = v1; s_red[s][h][2] = v2; }
  __syncthreads();   // B4

  if (h == 0 && lane == 0){
    float LC = s_red[s][0][0] + s_red[s][1][0];
    float LR = s_red[s][0][1] + s_red[s][1][1];
    float AC = s_red[s][0][2] + s_red[s][1][2];
    const int k_p = min(n_pos, 16);
    int denom = k_p + k_n; if (denom < 1) denom = 1;
    part[n]         = LC / (float)denom;
    part[N + n]     = (n_pos > 0) ? (LR / (4.0f * (float)n_pos)) : 0.0f;
    part[2 * N + n] = AC * (1.0f / (float)A_TOT);
  }
}

__global__ void __launch_bounds__(256) reduce_kernel(const float* __restrict__ part,
                                                     float* __restrict__ out, int N)
{
  const int tid = threadIdx.x;
  float lc = 0.0f, lr = 0.0f, ac = 0.0f;
  for (int i = tid; i < N; i += 256){
    lc += part[i];
    lr += part[N + i];
    ac += part[2 * N + i];
  }
  __shared__ float s[12];
  #pragma unroll
  for (int off = 32; off > 0; off >>= 1){
    lc += __shfl_down(lc, off, 64);
    lr += __shfl_down(lr, off, 64);
    ac += __shfl_down(ac, off, 64);
  }
  const int wave = tid >> 6, lane = tid & 63;
  if (lane == 0){ s[wave] = lc; s[4 + wave] = lr; s[8 + wave] = ac; }
  __syncthreads();
  if (tid == 0){
    float LC = s[0] + s[1] + s[2] + s[3];
    float LR = s[4] + s[5] + s[6] + s[7];
    float AC = s[8] + s[9] + s[10] + s[11];
    float inv = 1.0f / (float)N;
    LC *= inv; LR *= inv; AC *= inv;
    out[0] = LC + LR;
    out[1] = LC;
    out[2] = LR;
    out[3] = AC;
  }
}

extern "C" void kernel_launch(void* const* d_in, const int* in_sizes, int n_in,
                              void* d_out, int out_size, void* d_ws, size_t ws_size,
                              hipStream_t stream)
{
  const float* pred_cls = (const float*)d_in[0];
  const float* pred_reg = (const float*)d_in[1];
  const float* gt_bbox  = (const float*)d_in[2];
  const float* a_center = (const float*)d_in[3];
  const float* a_corner = (const float*)d_in[4];
  float* part = (float*)d_ws;            // 3*N floats
  float* out  = (float*)d_out;

  const int N = in_sizes[2] / 4;         // 4096

  hipLaunchKernelGGL(rpn_loss_kernel, dim3(N / SPB), dim3(SPB * 2 * 64), 0, stream,
                     pred_cls, pred_reg, gt_bbox, a_center, a_corner, part, N);
  hipLaunchKernelGGL(reduce_kernel, dim3(1), dim3(256), 0, stream, part, out, N);
}